// Round 3
// baseline (720.167 us; speedup 1.0000x reference)
//
#include <hip/hip_runtime.h>
#include <stdint.h>
#include <string.h>

#define NLEV 16

typedef float vf4 __attribute__((ext_vector_type(4)));

// ---------------------------------------------------------------------------
// Level index/weight helpers (exact reference semantics: int64 hash, fp32 math)
// ---------------------------------------------------------------------------
__device__ __forceinline__ void level_idx(
    float nx, float ny, float nz, int r, uint32_t sz, uint32_t off,
    uint32_t* __restrict__ idx, float& fx, float& fy, float& fz)
{
    const float rf = (float)r;
    const float px = nx * rf, py = ny * rf, pz = nz * rf;
    int bx = (int)floorf(px); bx = bx < 0 ? 0 : (bx > r - 1 ? r - 1 : bx);
    int by = (int)floorf(py); by = by < 0 ? 0 : (by > r - 1 ? r - 1 : by);
    int bz = (int)floorf(pz); bz = bz < 0 ? 0 : (bz > r - 1 ? r - 1 : bz);
    fx = px - (float)bx;
    fy = py - (float)by;
    fz = pz - (float)bz;

    const uint64_t hx0 = (uint64_t)(uint32_t)bx;
    const uint64_t hx1 = hx0 + 1u;
    const uint64_t hy0 = (uint64_t)(uint32_t)by       * 2654435761ull;
    const uint64_t hy1 = (uint64_t)(uint32_t)(by + 1) * 2654435761ull;
    const uint64_t hz0 = (uint64_t)(uint32_t)bz       * 805459861ull;
    const uint64_t hz1 = (uint64_t)(uint32_t)(bz + 1) * 805459861ull;

    const uint64_t yz00 = hy0 ^ hz0, yz01 = hy0 ^ hz1;
    const uint64_t yz10 = hy1 ^ hz0, yz11 = hy1 ^ hz1;

    idx[0] = (uint32_t)((hx0 ^ yz00) % sz) + off;
    idx[1] = (uint32_t)((hx0 ^ yz01) % sz) + off;
    idx[2] = (uint32_t)((hx0 ^ yz10) % sz) + off;
    idx[3] = (uint32_t)((hx0 ^ yz11) % sz) + off;
    idx[4] = (uint32_t)((hx1 ^ yz00) % sz) + off;
    idx[5] = (uint32_t)((hx1 ^ yz01) % sz) + off;
    idx[6] = (uint32_t)((hx1 ^ yz10) % sz) + off;
    idx[7] = (uint32_t)((hx1 ^ yz11) % sz) + off;
}

__device__ __forceinline__ void level_acc(
    const float2* __restrict__ v, float fx, float fy, float fz,
    float& f0, float& f1)
{
    const float gx = 1.0f - fx, gy = 1.0f - fy, gz = 1.0f - fz;
    const float w00 = gx * gy, w01 = gx * fy, w10 = fx * gy, w11 = fx * fy;
    float w;
    w = w00 * gz; f0 = w * v[0].x;          f1 = w * v[0].y;
    w = w00 * fz; f0 = fmaf(w, v[1].x, f0); f1 = fmaf(w, v[1].y, f1);
    w = w01 * gz; f0 = fmaf(w, v[2].x, f0); f1 = fmaf(w, v[2].y, f1);
    w = w01 * fz; f0 = fmaf(w, v[3].x, f0); f1 = fmaf(w, v[3].y, f1);
    w = w10 * gz; f0 = fmaf(w, v[4].x, f0); f1 = fmaf(w, v[4].y, f1);
    w = w10 * fz; f0 = fmaf(w, v[5].x, f0); f1 = fmaf(w, v[5].y, f1);
    w = w11 * gz; f0 = fmaf(w, v[6].x, f0); f1 = fmaf(w, v[6].y, f1);
    w = w11 * fz; f0 = fmaf(w, v[7].x, f0); f1 = fmaf(w, v[7].y, f1);
}

// ---------------------------------------------------------------------------
// Big levels (7..15): pow2 size -> 32-bit hash + AND. 4 points per thread for
// 32 gathers in flight. xyz via float4, ws store via 2x16B nontemporal.
// ---------------------------------------------------------------------------
template<int R, uint32_t OFF>
__global__ __launch_bounds__(256) void big_level4(
    const float* __restrict__ xyz,
    const float2* __restrict__ emb,
    float2* __restrict__ ws,
    int nb)
{
    const int t  = blockIdx.x * 256 + threadIdx.x;
    const int p0 = t * 4;
    if (p0 >= nb) return;   // nb % 4 == 0: quads are all-or-nothing

    const vf4* xyz4 = (const vf4*)xyz;
    const vf4 c0 = __builtin_nontemporal_load(xyz4 + 3 * (size_t)t);
    const vf4 c1 = __builtin_nontemporal_load(xyz4 + 3 * (size_t)t + 1);
    const vf4 c2 = __builtin_nontemporal_load(xyz4 + 3 * (size_t)t + 2);

    const float xs[4] = {c0.x, c0.w, c1.z, c2.y};
    const float ys[4] = {c0.y, c1.x, c1.w, c2.z};
    const float zs[4] = {c0.z, c1.y, c2.x, c2.w};

    uint32_t idx[4][8];
    float fx[4], fy[4], fz[4];
    const uint32_t M = 524287u;
    const float inv = 1.0f / 1.5f;

    #pragma unroll
    for (int q = 0; q < 4; ++q) {
        const float nx = (xs[q] + 0.75f) * inv;
        const float ny = (ys[q] + 0.75f) * inv;
        const float nz = (zs[q] + 0.75f) * inv;
        const float rf = (float)R;
        const float px = nx * rf, py = ny * rf, pz = nz * rf;
        int bx = (int)floorf(px); bx = bx < 0 ? 0 : (bx > R - 1 ? R - 1 : bx);
        int by = (int)floorf(py); by = by < 0 ? 0 : (by > R - 1 ? R - 1 : by);
        int bz = (int)floorf(pz); bz = bz < 0 ? 0 : (bz > R - 1 ? R - 1 : bz);
        fx[q] = px - (float)bx;
        fy[q] = py - (float)by;
        fz[q] = pz - (float)bz;

        const uint32_t hx0 = (uint32_t)bx;
        const uint32_t hx1 = hx0 + 1u;
        const uint32_t hy0 = (uint32_t)by       * 2654435761u;
        const uint32_t hy1 = (uint32_t)(by + 1) * 2654435761u;
        const uint32_t hz0 = (uint32_t)bz       * 805459861u;
        const uint32_t hz1 = (uint32_t)(bz + 1) * 805459861u;
        const uint32_t yz00 = hy0 ^ hz0, yz01 = hy0 ^ hz1;
        const uint32_t yz10 = hy1 ^ hz0, yz11 = hy1 ^ hz1;

        idx[q][0] = ((hx0 ^ yz00) & M) + OFF;
        idx[q][1] = ((hx0 ^ yz01) & M) + OFF;
        idx[q][2] = ((hx0 ^ yz10) & M) + OFF;
        idx[q][3] = ((hx0 ^ yz11) & M) + OFF;
        idx[q][4] = ((hx1 ^ yz00) & M) + OFF;
        idx[q][5] = ((hx1 ^ yz01) & M) + OFF;
        idx[q][6] = ((hx1 ^ yz10) & M) + OFF;
        idx[q][7] = ((hx1 ^ yz11) & M) + OFF;
    }

    float2 v[4][8];
    #pragma unroll
    for (int q = 0; q < 4; ++q)
        #pragma unroll
        for (int c = 0; c < 8; ++c)
            v[q][c] = emb[idx[q][c]];

    float f0[4], f1[4];
    #pragma unroll
    for (int q = 0; q < 4; ++q)
        level_acc(v[q], fx[q], fy[q], fz[q], f0[q], f1[q]);

    vf4 a = {f0[0], f1[0], f0[1], f1[1]};
    vf4 b = {f0[2], f1[2], f0[3], f1[3]};
    vf4* dst = (vf4*)(ws + p0);
    __builtin_nontemporal_store(a, dst);
    __builtin_nontemporal_store(b, dst + 1);
}

// ---------------------------------------------------------------------------
// Pack: small levels 0..6 (tables 2.47 MB, L2-resident) with a 2-level
// software pipeline; merge big-level ws slices; coalesced out via LDS
// transpose (stride 35 coprime with 32 -> conflict-free).
// ---------------------------------------------------------------------------
__global__ __launch_bounds__(256, 4) void pack_small(
    const float* __restrict__ xyz,
    const float2* __restrict__ emb,
    const float2* __restrict__ ws,
    float* __restrict__ out,
    int nb)
{
    constexpr int      kRes[7]  = {16, 20, 25, 32, 40, 50, 64};
    constexpr uint32_t kSize[7] = {4913u, 9261u, 17576u, 35937u, 68921u, 132651u, 274625u};
    constexpr uint32_t kOff[7]  = {0u, 4913u, 14174u, 31750u, 67687u, 136608u, 269259u};

    __shared__ float lds[4 * 64 * 35];

    const int tid  = threadIdx.x;
    const int lane = tid & 63;
    const int wid  = tid >> 6;
    const int p    = blockIdx.x * 256 + tid;
    const int pc   = (p < nb) ? p : (nb - 1);

    // issue big-level ws loads first; hold in registers until the epilogue
    uint64_t big[9];
    #pragma unroll
    for (int l = 0; l < 9; ++l)
        big[l] = __builtin_nontemporal_load((const uint64_t*)ws + (size_t)l * nb + pc);

    const float x = xyz[3 * pc + 0];
    const float y = xyz[3 * pc + 1];
    const float z = xyz[3 * pc + 2];

    float* wl = &lds[(wid * 64 + lane) * 35];
    wl[0] = x; wl[1] = y; wl[2] = z;

    const float inv = 1.0f / 1.5f;
    const float nx = (x + 0.75f) * inv;
    const float ny = (y + 0.75f) * inv;
    const float nz = (z + 0.75f) * inv;

    // 2-stage software pipeline across the 7 small levels
    uint32_t idx[2][8];
    float    fxs[2], fys[2], fzs[2];
    float2   v[2][8];

    level_idx(nx, ny, nz, kRes[0], kSize[0], kOff[0], idx[0], fxs[0], fys[0], fzs[0]);
    #pragma unroll
    for (int c = 0; c < 8; ++c) v[0][c] = emb[idx[0][c]];

    #pragma unroll
    for (int l = 0; l < 7; ++l) {
        const int cur = l & 1, nxt = cur ^ 1;
        if (l < 6) {
            level_idx(nx, ny, nz, kRes[l + 1], kSize[l + 1], kOff[l + 1],
                      idx[nxt], fxs[nxt], fys[nxt], fzs[nxt]);
            #pragma unroll
            for (int c = 0; c < 8; ++c) v[nxt][c] = emb[idx[nxt][c]];
        }
        float f0, f1;
        level_acc(v[cur], fxs[cur], fys[cur], fzs[cur], f0, f1);
        wl[3 + 2 * l] = f0;
        wl[4 + 2 * l] = f1;
    }

    // merge big-level results
    #pragma unroll
    for (int l = 0; l < 9; ++l) {
        float2 bv;
        memcpy(&bv, &big[l], 8);
        wl[3 + 2 * (l + 7)] = bv.x;
        wl[4 + 2 * (l + 7)] = bv.y;
    }

    __syncthreads();

    const int wave_gid = blockIdx.x * 4 + wid;
    if (wave_gid * 64 < nb) {
        const float* src = &lds[wid * 64 * 35];
        float* dst = out + (size_t)wave_gid * (64 * 35);
        #pragma unroll
        for (int c = 0; c < 35; ++c)
            __builtin_nontemporal_store(src[c * 64 + lane], dst + c * 64 + lane);
    }
}

// ---------------------------------------------------------------------------
// Fallback: monolithic (only if ws_size < 72 MB)
// ---------------------------------------------------------------------------
__global__ __launch_bounds__(256, 4) void hashgrid_mono(
    const float* __restrict__ xyz,
    const float2* __restrict__ emb,
    float* __restrict__ out,
    int nb)
{
    constexpr int      kRes[NLEV]  = {16,20,25,32,40,50,64,80,101,128,161,203,256,322,406,512};
    constexpr uint32_t kSize[NLEV] = {4913u,9261u,17576u,35937u,68921u,132651u,274625u,
                                      524288u,524288u,524288u,524288u,524288u,
                                      524288u,524288u,524288u,524288u};
    constexpr uint32_t kOff[NLEV]  = {0u,4913u,14174u,31750u,67687u,136608u,269259u,543884u,
                                      1068172u,1592460u,2116748u,2641036u,3165324u,
                                      3689612u,4213900u,4738188u};

    __shared__ float lds[4 * 64 * 35];

    const int tid  = threadIdx.x;
    const int lane = tid & 63;
    const int wid  = tid >> 6;
    const int p    = blockIdx.x * 256 + tid;
    const int pc   = (p < nb) ? p : (nb - 1);

    const float x = xyz[3 * pc + 0];
    const float y = xyz[3 * pc + 1];
    const float z = xyz[3 * pc + 2];

    float* wl = &lds[(wid * 64 + lane) * 35];
    wl[0] = x; wl[1] = y; wl[2] = z;

    const float inv = 1.0f / 1.5f;
    const float nx = (x + 0.75f) * inv;
    const float ny = (y + 0.75f) * inv;
    const float nz = (z + 0.75f) * inv;

    #pragma unroll
    for (int l = 0; l < NLEV; ++l) {
        uint32_t idx[8];
        float fx, fy, fz;
        level_idx(nx, ny, nz, kRes[l], kSize[l], kOff[l], idx, fx, fy, fz);
        float2 v[8];
        #pragma unroll
        for (int c = 0; c < 8; ++c) v[c] = emb[idx[c]];
        float f0, f1;
        level_acc(v, fx, fy, fz, f0, f1);
        wl[3 + 2 * l] = f0;
        wl[4 + 2 * l] = f1;
    }

    __syncthreads();

    const int wave_gid = blockIdx.x * 4 + wid;
    if (wave_gid * 64 < nb) {
        const float* src = &lds[wid * 64 * 35];
        float* dst = out + (size_t)wave_gid * (64 * 35);
        #pragma unroll
        for (int c = 0; c < 35; ++c)
            dst[c * 64 + lane] = src[c * 64 + lane];
    }
}

// ---------------------------------------------------------------------------
extern "C" void kernel_launch(void* const* d_in, const int* in_sizes, int n_in,
                              void* d_out, int out_size, void* d_ws, size_t ws_size,
                              hipStream_t stream) {
    const float*  xyz = (const float*)d_in[0];
    const float2* emb = (const float2*)d_in[1];
    float*        out = (float*)d_out;
    const int nb = in_sizes[0] / 3;           // 1,000,000
    const int blocks = (nb + 255) / 256;      // 3907

    const size_t ws_need = (size_t)9 * (size_t)nb * sizeof(float2);  // 72 MB
    if (ws_size < ws_need) {
        hashgrid_mono<<<blocks, 256, 0, stream>>>(xyz, emb, out, nb);
        return;
    }

    float2* ws = (float2*)d_ws;
    const int blocks4 = (nb / 4 + 255) / 256;  // 977
    big_level4< 80,  543884u><<<blocks4, 256, 0, stream>>>(xyz, emb, ws + (size_t)0 * nb, nb);
    big_level4<101, 1068172u><<<blocks4, 256, 0, stream>>>(xyz, emb, ws + (size_t)1 * nb, nb);
    big_level4<128, 1592460u><<<blocks4, 256, 0, stream>>>(xyz, emb, ws + (size_t)2 * nb, nb);
    big_level4<161, 2116748u><<<blocks4, 256, 0, stream>>>(xyz, emb, ws + (size_t)3 * nb, nb);
    big_level4<203, 2641036u><<<blocks4, 256, 0, stream>>>(xyz, emb, ws + (size_t)4 * nb, nb);
    big_level4<256, 3165324u><<<blocks4, 256, 0, stream>>>(xyz, emb, ws + (size_t)5 * nb, nb);
    big_level4<322, 3689612u><<<blocks4, 256, 0, stream>>>(xyz, emb, ws + (size_t)6 * nb, nb);
    big_level4<406, 4213900u><<<blocks4, 256, 0, stream>>>(xyz, emb, ws + (size_t)7 * nb, nb);
    big_level4<512, 4738188u><<<blocks4, 256, 0, stream>>>(xyz, emb, ws + (size_t)8 * nb, nb);
    pack_small<<<blocks, 256, 0, stream>>>(xyz, emb, ws, out, nb);
}